// Round 10
// baseline (97.853 us; speedup 1.0000x reference)
//
#include <hip/hip_runtime.h>
#include <cstddef>

// MPS classifier: SIZE=784, D=32, DLOC=2, NUM_LABELS=10, LABEL_SITE=392, B=128
//
// Round-10: remove the per-site blend/unpack VALU from kchain.
//  - Site update rewritten as acc += E0*B + D*Bx with B = bf16(P),
//    Bx = bf16(x*P) (x is wave-uniform): E0 = M0-I and D = M1-M0 are stored
//    PRE-PACKED bf16 in core2b and feed the MFMA A-operand directly (no
//    shl/and/fma/pack per site). 16 MFMAs/site (MFMA pipe was ~5% busy),
//    VALU/site ~80 -> ~40.
//  - x loaded once per segment (lane l holds x[s_lo+l]) and broadcast per
//    site via __shfl (1 instr, no LDS).
//  - __launch_bounds__(512, 8) pins 8 waves/SIMD (est ~55 VGPR <= 64).
//  - T-world LDS tree fold and gfin unchanged from verified round 9.
// core2b site layout: uint4 per (frag f=r*2+h2, lane): {e0_j01, e0_j23,
//   d_j01, d_j23} (bf16 pairs). ws: [core2b 3.2MB][halfbuf 2MB].

typedef short bfrag __attribute__((ext_vector_type(4)));   // 4 bf16
typedef float facc  __attribute__((ext_vector_type(4)));   // 4 fp32

#if !defined(__HIP_DEVICE_COMPILE__)
#define MFMA16(a, b, c) (c)  // host-pass stub (host clang lacks amdgcn builtins)
#elif __has_builtin(__builtin_amdgcn_mfma_f32_16x16x16bf16_1k)
#define MFMA16(a, b, c) __builtin_amdgcn_mfma_f32_16x16x16bf16_1k(a, b, c, 0, 0, 0)
#elif __has_builtin(__builtin_amdgcn_mfma_f32_16x16x16_bf16)
#define MFMA16(a, b, c) __builtin_amdgcn_mfma_f32_16x16x16_bf16(a, b, c, 0, 0, 0)
#else
#error "no 16x16x16 bf16 MFMA builtin on this target"
#endif

#define CORE2B_DWORDS (784 * 1024)

__device__ __forceinline__ short bf16h(float v) {
  unsigned u = __float_as_uint(v) + 0x8000u;  // round-half-up to bf16
  return (short)(u >> 16);
}

// pack 4 fp32 -> 4 bf16 (HW cvt_pk on gfx950, manual fallback)
#if defined(__HIP_DEVICE_COMPILE__) && __has_builtin(__builtin_amdgcn_cvt_pk_bf16_f32)
typedef __bf16 bf16x2 __attribute__((ext_vector_type(2)));
__device__ __forceinline__ bfrag packf4(float a, float b, float c, float d) {
  bf16x2 lo = __builtin_amdgcn_cvt_pk_bf16_f32(a, b);
  bf16x2 hi = __builtin_amdgcn_cvt_pk_bf16_f32(c, d);
  uint2 u = make_uint2(__builtin_bit_cast(unsigned, lo), __builtin_bit_cast(unsigned, hi));
  return __builtin_bit_cast(bfrag, u);
}
#else
__device__ __forceinline__ bfrag packf4(float a, float b, float c, float d) {
  bfrag r; r[0] = bf16h(a); r[1] = bf16h(b); r[2] = bf16h(c); r[3] = bf16h(d);
  return r;
}
#endif

// fp32 -> (hi bf16 rounded, lo bf16 of remainder) — cold path (folds only)
__device__ __forceinline__ void split4(const float* v, bfrag& hi, bfrag& lo) {
#pragma unroll
  for (int j = 0; j < 4; ++j) {
    unsigned u = (__float_as_uint(v[j]) + 0x8000u) & 0xFFFF0000u;
    hi[j] = (short)(u >> 16);
    float lf = v[j] - __uint_as_float(u);
    lo[j] = bf16h(lf);
  }
}

// One fold step: acc <- A * acc (3-term bf16 hi/lo split).
// av[R][H] = float4 A-frag: A[16R+col16][16H+4q .. +3].
__device__ __forceinline__ void fold_step(facc (&acc)[2][2], const float4 (&av)[2][2]) {
  bfrag Ahi[2][2], Alo[2][2], Bhi[2][2], Blo[2][2];
#pragma unroll
  for (int R = 0; R < 2; ++R)
#pragma unroll
    for (int H = 0; H < 2; ++H) {
      float v[4] = {av[R][H].x, av[R][H].y, av[R][H].z, av[R][H].w};
      split4(v, Ahi[R][H], Alo[R][H]);
    }
#pragma unroll
  for (int H = 0; H < 2; ++H)
#pragma unroll
    for (int c = 0; c < 2; ++c) {
      float v[4] = {acc[H][c][0], acc[H][c][1], acc[H][c][2], acc[H][c][3]};
      split4(v, Bhi[H][c], Blo[H][c]);
    }
  facc n[2][2];
#pragma unroll
  for (int R = 0; R < 2; ++R)
#pragma unroll
    for (int c = 0; c < 2; ++c) {
      facc z;
#pragma unroll
      for (int j = 0; j < 4; ++j) z[j] = 0.0f;
#pragma unroll
      for (int H = 0; H < 2; ++H) {
        z = MFMA16(Ahi[R][H], Bhi[H][c], z);
        z = MFMA16(Ahi[R][H], Blo[H][c], z);
        z = MFMA16(Alo[R][H], Bhi[H][c], z);
      }
      n[R][c] = z;
    }
#pragma unroll
  for (int R = 0; R < 2; ++R)
#pragma unroll
    for (int c = 0; c < 2; ++c) acc[R][c] = n[R][c];
}

// ---------------------------------------------------------------------------
// K0: core -> core2b. Coalesced reads; per source float4 (elements (i,c) and
// (i,c+1)) emit the bf16 e0-pair dword and d-pair dword into the uint4 slot
// of frag f = r*2+h2, lane = col16+16q:  [e0_j01, e0_j23, d_j01, d_j23].
// ---------------------------------------------------------------------------
__global__ __launch_bounds__(256) void xform_k(const float* __restrict__ core,
                                               unsigned* __restrict__ core2b) {
  const int s = blockIdx.x;  // 0..783
  const int tid = threadIdx.x;
  const float4* src = (const float4*)(core + (size_t)s * 2048);
  unsigned* dst = core2b + (size_t)s * 1024;
#pragma unroll
  for (int u = 0; u < 2; ++u) {
    int v = tid + 256 * u;  // 0..511, coalesced
    float4 f = src[v];
    int i = v >> 4;
    int c = (v & 15) * 2;
    int r = i >> 4, col16 = i & 15;
    int h2 = c >> 4, cl = c & 15;
    int q = cl >> 2, j = cl & 3;  // j in {0,2}
    int lane = col16 + 16 * q;
    int slot = (r * 2 + h2) * 64 + lane;
    float e0a = f.x - ((i == c) ? 1.0f : 0.0f);
    float e0b = f.z - ((i == c + 1) ? 1.0f : 0.0f);
    unsigned e0pair = ((unsigned)(unsigned short)bf16h(e0b) << 16) |
                      (unsigned)(unsigned short)bf16h(e0a);
    unsigned dpair = ((unsigned)(unsigned short)bf16h(f.w - f.z) << 16) |
                     (unsigned)(unsigned short)bf16h(f.y - f.x);
    dst[4 * slot + (j >> 1)] = e0pair;
    dst[4 * slot + 2 + (j >> 1)] = dpair;
  }
}

// ---------------------------------------------------------------------------
// K1 kchain: 512 blocks x 512 thr. bid -> chain = bid>>1, half = bid&1.
// Wave k (0..7) runs segment t = half*8 + k site loop (acc += E0*B + D*Bx),
// then 3-level T-world LDS tree fold -> half-chain product X, row-major.
// ---------------------------------------------------------------------------
__global__ __launch_bounds__(512, 8) void kchain(const float* __restrict__ x,
                                                 const unsigned* __restrict__ core2b,
                                                 float* __restrict__ halfbuf) {
  const int tid = threadIdx.x;
  const int lane = tid & 63;
  const int k = tid >> 6;  // wave 0..7
  const int col16 = lane & 15;
  const int q = lane >> 4;

  const int bid = blockIdx.x;   // 0..511
  const int chain = bid >> 1;   // 0..255 = b*2 + hside
  const int half = bid & 1;
  const int b = chain >> 1;
  const int hside = chain & 1;

  const int t = half * 8 + k;  // global segment 0..15
  const int start = (t < 8) ? 25 * t : 200 + 24 * (t - 8);
  const int len = (t < 8) ? 25 : 24;
  const int s_lo = hside * 392 + start;
  const int s_hi = s_lo + len - 1;

  __shared__ float smX[8][32 * 36];  // padded row-major slots (stride 36)

  facc acc[2][2];
#pragma unroll
  for (int r = 0; r < 2; ++r)
#pragma unroll
    for (int c = 0; c < 2; ++c)
#pragma unroll
      for (int j = 0; j < 4; ++j)
        acc[r][c][j] = (16 * r + 4 * q + j == 16 * c + col16) ? 1.0f : 0.0f;

  const uint4* cp = (const uint4*)core2b;
  const float* xb = x + b * 784;

  // stage this segment's x values across lanes; broadcast per site via shfl
  float xr = (lane < len) ? xb[s_lo + lane] : 0.0f;

  // ---- segment site loop: acc = S_t (C/D layout) ----
  for (int s = s_hi; s >= s_lo; --s) {
    uint4 raw[4];  // frag f = r*2+h2: {e0_j01, e0_j23, d_j01, d_j23}
#pragma unroll
    for (int f = 0; f < 4; ++f) raw[f] = cp[(size_t)s * 256 + f * 64 + lane];
    const float xv = __shfl(xr, s - s_lo, 64);

    // snapshot B = bf16(P), Bx = bf16(xv*P) BEFORE any accumulation
    // (C/D layout == B layout for K=16)
    bfrag B[2][2], Bx[2][2];
#pragma unroll
    for (int h2 = 0; h2 < 2; ++h2)
#pragma unroll
      for (int c = 0; c < 2; ++c) {
        facc a = acc[h2][c];
        B[h2][c] = packf4(a[0], a[1], a[2], a[3]);
        Bx[h2][c] = packf4(xv * a[0], xv * a[1], xv * a[2], xv * a[3]);
      }

    // acc += E0*B + D*Bx   (16 MFMAs, A-operands straight from the load)
#pragma unroll
    for (int r = 0; r < 2; ++r)
#pragma unroll
      for (int h2 = 0; h2 < 2; ++h2) {
        const uint4 rw = raw[r * 2 + h2];
        bfrag E0 = __builtin_bit_cast(bfrag, make_uint2(rw.x, rw.y));
        bfrag Dd = __builtin_bit_cast(bfrag, make_uint2(rw.z, rw.w));
#pragma unroll
        for (int c = 0; c < 2; ++c) {
          acc[r][c] = MFMA16(Dd, Bx[h2][c], acc[r][c]);
          acc[r][c] = MFMA16(E0, B[h2][c], acc[r][c]);
        }
      }
  }

  // ---- publish T_k = S_t^T row-major (fragment-level transpose, f4 store) ----
#pragma unroll
  for (int r = 0; r < 2; ++r)
#pragma unroll
    for (int c = 0; c < 2; ++c)
      *(float4*)&smX[k][(16 * c + col16) * 36 + 16 * r + 4 * q] =
          make_float4(acc[r][c][0], acc[r][c][1], acc[r][c][2], acc[r][c][3]);
  __syncthreads();

  // consumer A-frag read of slot m gives A-frags of T_m (row-major source).
  facc a2[2][2];
#pragma unroll
  for (int r = 0; r < 2; ++r)
#pragma unroll
    for (int c = 0; c < 2; ++c)
#pragma unroll
      for (int j = 0; j < 4; ++j)
        a2[r][c][j] = (16 * r + 4 * q + j == 16 * c + col16) ? 1.0f : 0.0f;

  const int fo0 = (16 * 0 + col16) * 36 + 4 * q;
  const int fo1 = (16 * 1 + col16) * 36 + 4 * q;

  // L1: even waves fold pair (k, k+1): a2 = T_{k+1} * T_k
  if ((k & 1) == 0) {
    float4 av[2][2];
#pragma unroll
    for (int R = 0; R < 2; ++R)
#pragma unroll
      for (int H = 0; H < 2; ++H)
        av[R][H] = *(const float4*)&smX[k][(R ? fo1 : fo0) + 16 * H];
    fold_step(a2, av);  // = T_k
#pragma unroll
    for (int R = 0; R < 2; ++R)
#pragma unroll
      for (int H = 0; H < 2; ++H)
        av[R][H] = *(const float4*)&smX[k + 1][(R ? fo1 : fo0) + 16 * H];
    fold_step(a2, av);  // = T_{k+1} T_k
  }
  __syncthreads();
  // producers of L2: waves 2, 6 publish (a2 already T-world: row-major write)
  if (k == 2 || k == 6) {
#pragma unroll
    for (int r = 0; r < 2; ++r)
#pragma unroll
      for (int c = 0; c < 2; ++c)
#pragma unroll
        for (int j = 0; j < 4; ++j)
          smX[k][(16 * r + 4 * q + j) * 36 + 16 * c + col16] = a2[r][c][j];
  }
  __syncthreads();
  // L2: waves 0, 4 fold partner k+2
  if (k == 0 || k == 4) {
    float4 av[2][2];
#pragma unroll
    for (int R = 0; R < 2; ++R)
#pragma unroll
      for (int H = 0; H < 2; ++H)
        av[R][H] = *(const float4*)&smX[k + 2][(R ? fo1 : fo0) + 16 * H];
    fold_step(a2, av);  // = T_{k+3..k}
  }
  __syncthreads();
  // producer of L3: wave 4 publishes
  if (k == 4) {
#pragma unroll
    for (int r = 0; r < 2; ++r)
#pragma unroll
      for (int c = 0; c < 2; ++c)
#pragma unroll
        for (int j = 0; j < 4; ++j)
          smX[4][(16 * r + 4 * q + j) * 36 + 16 * c + col16] = a2[r][c][j];
  }
  __syncthreads();
  // L3: wave 0 folds slot 4 -> X = T_{half*8+7}...T_{half*8}; store row-major
  if (k == 0) {
    float4 av[2][2];
#pragma unroll
    for (int R = 0; R < 2; ++R)
#pragma unroll
      for (int H = 0; H < 2; ++H)
        av[R][H] = *(const float4*)&smX[4][(R ? fo1 : fo0) + 16 * H];
    fold_step(a2, av);
    float* rm = halfbuf + (size_t)bid * 1024;  // bid = chain*2 + half
#pragma unroll
    for (int r = 0; r < 2; ++r)
#pragma unroll
      for (int c = 0; c < 2; ++c)
#pragma unroll
        for (int j = 0; j < 4; ++j)
          rm[(16 * r + 4 * q + j) * 32 + 16 * c + col16] = a2[r][c][j];
  }
}

// ---------------------------------------------------------------------------
// K2 gfin: 128 blocks x 64 thr.
// H = Left^T * Right^T = X_L1 * X_L0 * X_R1 * X_R0 : 4 fold_steps from I,
// A-frags read from row-major half products. Then label contraction.
// ---------------------------------------------------------------------------
__global__ __launch_bounds__(64) void gfin(const float* __restrict__ halfbuf,
                                           const float* __restrict__ label,
                                           float* __restrict__ out) {
  const int lane = threadIdx.x;
  const int b = blockIdx.x;
  const int col16 = lane & 15;
  const int q = lane >> 4;

  __shared__ float smF[1024];

  facc acc[2][2];
#pragma unroll
  for (int r = 0; r < 2; ++r)
#pragma unroll
    for (int c = 0; c < 2; ++c)
#pragma unroll
      for (int j = 0; j < 4; ++j)
        acc[r][c][j] = (16 * r + 4 * q + j == 16 * c + col16) ? 1.0f : 0.0f;

  // fold order: X_R0, X_R1, X_L0, X_L1  (slot = chain*2 + half)
  const int slots[4] = {(2 * b + 1) * 2 + 0, (2 * b + 1) * 2 + 1,
                        (2 * b) * 2 + 0, (2 * b) * 2 + 1};
#pragma unroll
  for (int m = 0; m < 4; ++m) {
    const float* rm = halfbuf + (size_t)slots[m] * 1024;
    float4 av[2][2];
#pragma unroll
    for (int R = 0; R < 2; ++R)
#pragma unroll
      for (int H = 0; H < 2; ++H)
        av[R][H] = *(const float4*)&rm[(16 * R + col16) * 32 + 16 * H + 4 * q];
    fold_step(acc, av);
  }

  // acc = H = F^T (C/D layout); smF[j*32+k] = H[j][k]; label[(j*32+k)*10+l]
#pragma unroll
  for (int r = 0; r < 2; ++r)
#pragma unroll
    for (int c = 0; c < 2; ++c)
#pragma unroll
      for (int j = 0; j < 4; ++j)
        smF[(16 * r + 4 * q + j) * 32 + 16 * c + col16] = acc[r][c][j];
  __syncthreads();

  float part[10];
#pragma unroll
  for (int l = 0; l < 10; ++l) part[l] = 0.0f;
#pragma unroll
  for (int u = 0; u < 16; ++u) {
    int e = lane + 64 * u;
    float v = smF[e];
    const float* lb = label + (size_t)e * 10;
#pragma unroll
    for (int l = 0; l < 10; ++l) part[l] += v * lb[l];
  }
#pragma unroll
  for (int l = 0; l < 10; ++l) {
#pragma unroll
    for (int o = 32; o > 0; o >>= 1) part[l] += __shfl_xor(part[l], o, 64);
  }
  if (lane == 0) {
#pragma unroll
    for (int l = 0; l < 10; ++l) out[b * 10 + l] = part[l];
  }
}

extern "C" void kernel_launch(void* const* d_in, const int* in_sizes, int n_in,
                              void* d_out, int out_size, void* d_ws, size_t ws_size,
                              hipStream_t stream) {
  const float* x = (const float*)d_in[0];      // (128, 784)
  const float* core = (const float*)d_in[1];   // (784, 32, 32, 2)
  const float* label = (const float*)d_in[2];  // (32, 32, 10)
  float* out = (float*)d_out;                  // (128, 10)

  unsigned* core2b = (unsigned*)d_ws;                 // 3.2 MB
  float* halfbuf = (float*)d_ws + CORE2B_DWORDS;      // 2 MB

  hipLaunchKernelGGL(xform_k, dim3(784), dim3(256), 0, stream, core, core2b);
  hipLaunchKernelGGL(kchain, dim3(512), dim3(512), 0, stream, x, core2b, halfbuf);
  hipLaunchKernelGGL(gfin, dim3(128), dim3(64), 0, stream, halfbuf, label, out);
}